// Round 2
// baseline (361.905 us; speedup 1.0000x reference)
//
#include <hip/hip_runtime.h>
#include <hip/hip_bf16.h>

// ---------- types ----------
using f32x4  = __attribute__((ext_vector_type(4))) float;
using bf16x8 = __attribute__((ext_vector_type(8))) short;   // 8 bf16 (4 VGPRs)

#define MFMA16(a, b, c) __builtin_amdgcn_mfma_f32_16x16x32_bf16((a), (b), (c), 0, 0, 0)

static __device__ __forceinline__ unsigned short f2bf(float x) {
    unsigned int u = __builtin_bit_cast(unsigned int, x);
    unsigned int r = (u + 0x7fffu + ((u >> 16) & 1u)) >> 16;
    return (unsigned short)r;
}

// ---------- geometry ----------
// b=4, c(dim)=256, n=2048, heads=8, dhead=64, hidden=512, 3*hidden=1536
#define NB 4
#define DIMC 256
#define NN 2048
#define NH 8
#define DH 64
#define HID 512

// workspace offsets (bytes)
#define OFF_XT  0u            // [4][2048][256] bf16 : 4 MiB
#define OFF_WQ  4194304u      // [1536][256]    bf16 : 768 KiB
#define OFF_WO  4980736u      // [256][512]     bf16 : 256 KiB
#define OFF_Q   5242880u      // [4][8][2048][64] bf16 : 8 MiB  (scaled q, [n][d] per head)
#define OFF_K   13631488u     // [4][8][2048][64] bf16 : 8 MiB
#define OFF_V   22020096u     // [4][512][2048]   bf16 : 8 MiB  ([h*64+d][n] per batch)
#define OFF_AO  30408704u     // [4][2048][512]   bf16 : 8 MiB  (attn out, [n][hid])
// total 38,797,312 bytes

// ---------- stage 0a: weights -> bf16 ----------
__global__ __launch_bounds__(256) void k_convert_w(
    const float* __restrict__ wqkv, const float* __restrict__ wout,
    unsigned short* __restrict__ wq_b, unsigned short* __restrict__ wo_b)
{
    int i = blockIdx.x * 256 + threadIdx.x;
    if (i < 1536 * 256) wq_b[i] = f2bf(wqkv[i]);
    if (i < 256 * 512)  wo_b[i] = f2bf(wout[i]);
}

// ---------- stage 0b: x[b][c][n] -> xt[b][n][c] bf16 ----------
__global__ __launch_bounds__(256) void k_transpose_x(
    const float* __restrict__ x, unsigned short* __restrict__ xt)
{
    __shared__ unsigned short tile[64][65];
    int nb = blockIdx.x;   // n-tile 0..31
    int cb = blockIdx.y;   // c-tile 0..3
    int b  = blockIdx.z;
    int t  = threadIdx.x;
    int tn = t & 63, tg = t >> 6;
    const float* xp = x + ((size_t)(b * DIMC + cb * 64)) * NN + nb * 64;
#pragma unroll
    for (int it = 0; it < 16; ++it) {
        int c = tg * 16 + it;
        tile[c][tn] = f2bf(xp[(size_t)c * NN + tn]);
    }
    __syncthreads();
    unsigned short* op = xt + ((size_t)(b * NN + nb * 64)) * DIMC + cb * 64;
#pragma unroll
    for (int it = 0; it < 16; ++it) {
        int n = tg * 16 + it;
        op[(size_t)n * DIMC + tn] = tile[tn][n];
    }
}

// ---------- stage 1: qkv = w_qkv @ x ----------
// o-tiles 0..15 (q,k): transposed flavor, D[n][o], writes [b][h][n][d]
// o-tiles 16..23 (v):  normal flavor,     D[o][n], writes [b][o-1024][n]
__global__ __launch_bounds__(256) void k_qkv(
    const unsigned short* __restrict__ wq,  // [1536][256]
    const unsigned short* __restrict__ xt,  // [4][2048][256]
    unsigned short* __restrict__ qT, unsigned short* __restrict__ kT,
    unsigned short* __restrict__ vW)
{
    int bx = blockIdx.x;          // o-tile 0..23
    int nb = blockIdx.y;          // n-tile 0..31
    int b  = blockIdx.z;
    int wid = threadIdx.x >> 6;
    int l = threadIdx.x & 63, l15 = l & 15, l4 = l >> 4;
    int o0 = bx * 64, n0 = nb * 64;
    int wr = wid >> 1, wc = wid & 1;
    f32x4 acc[2][2] = {};

    if (bx < 16) {
        // A = xt rows (n), B = wq cols (o)
        const unsigned short* arow = xt + ((size_t)(b * NN + n0 + wr * 32)) * DIMC;
        const unsigned short* brow = wq + (size_t)(o0 + wc * 32) * DIMC;
#pragma unroll
        for (int k0 = 0; k0 < DIMC; k0 += 32) {
            int koff = k0 + l4 * 8;
            bf16x8 a0 = *(const bf16x8*)(arow + (size_t)l15 * DIMC + koff);
            bf16x8 a1 = *(const bf16x8*)(arow + (size_t)(l15 + 16) * DIMC + koff);
            bf16x8 b0 = *(const bf16x8*)(brow + (size_t)l15 * DIMC + koff);
            bf16x8 b1 = *(const bf16x8*)(brow + (size_t)(l15 + 16) * DIMC + koff);
            acc[0][0] = MFMA16(a0, b0, acc[0][0]);
            acc[0][1] = MFMA16(a0, b1, acc[0][1]);
            acc[1][0] = MFMA16(a1, b0, acc[1][0]);
            acc[1][1] = MFMA16(a1, b1, acc[1][1]);
        }
#pragma unroll
        for (int fm = 0; fm < 2; ++fm)
#pragma unroll
            for (int fn = 0; fn < 2; ++fn) {
                int ocol = o0 + wc * 32 + fn * 16 + l15;
#pragma unroll
                for (int r = 0; r < 4; ++r) {
                    int nrow = n0 + wr * 32 + fm * 16 + l4 * 4 + r;
                    float v = acc[fm][fn][r];
                    if (ocol < HID) {  // q, scaled
                        int h = ocol >> 6, d = ocol & 63;
                        qT[(((size_t)(b * NH + h)) * NN + nrow) * DH + d] = f2bf(v * 0.125f);
                    } else {           // k
                        int o2 = ocol - HID;
                        kT[(((size_t)(b * NH + (o2 >> 6))) * NN + nrow) * DH + (o2 & 63)] = f2bf(v);
                    }
                }
            }
    } else {
        // A = wq rows (o), B = xt cols (n)
        const unsigned short* arow = wq + (size_t)(o0 + wr * 32) * DIMC;
        const unsigned short* brow = xt + ((size_t)(b * NN + n0 + wc * 32)) * DIMC;
#pragma unroll
        for (int k0 = 0; k0 < DIMC; k0 += 32) {
            int koff = k0 + l4 * 8;
            bf16x8 a0 = *(const bf16x8*)(arow + (size_t)l15 * DIMC + koff);
            bf16x8 a1 = *(const bf16x8*)(arow + (size_t)(l15 + 16) * DIMC + koff);
            bf16x8 b0 = *(const bf16x8*)(brow + (size_t)l15 * DIMC + koff);
            bf16x8 b1 = *(const bf16x8*)(brow + (size_t)(l15 + 16) * DIMC + koff);
            acc[0][0] = MFMA16(a0, b0, acc[0][0]);
            acc[0][1] = MFMA16(a0, b1, acc[0][1]);
            acc[1][0] = MFMA16(a1, b0, acc[1][0]);
            acc[1][1] = MFMA16(a1, b1, acc[1][1]);
        }
#pragma unroll
        for (int fm = 0; fm < 2; ++fm)
#pragma unroll
            for (int fn = 0; fn < 2; ++fn)
#pragma unroll
                for (int r = 0; r < 4; ++r) {
                    int orow = o0 + wr * 32 + fm * 16 + l4 * 4 + r;       // 1024..1535
                    int ncol = n0 + wc * 32 + fn * 16 + l15;
                    vW[((size_t)(b * HID + orow - 1024)) * NN + ncol] = f2bf(acc[fm][fn][r]);
                }
    }
}

// ---------- stage 2: flash attention ----------
// grid (32 i-tiles, 32 b*h); 4 waves x 16 query rows; JBLK=64
__global__ __launch_bounds__(256) void k_attn(
    const unsigned short* __restrict__ qT, const unsigned short* __restrict__ kT,
    const unsigned short* __restrict__ vW, unsigned short* __restrict__ ao)
{
    __shared__ unsigned short plds[4][1024];  // per-wave 16x64 bf16, XOR-swizzled
    int it = blockIdx.x;
    int bh = blockIdx.y;
    int b = bh >> 3, h = bh & 7;
    int wid = threadIdx.x >> 6;
    int l = threadIdx.x & 63, l15 = l & 15, l4 = l >> 4;
    int i0 = it * 64 + wid * 16;

    const unsigned short* qbase = qT + ((size_t)bh * NN) * DH;
    const unsigned short* kbase = kT + ((size_t)bh * NN) * DH;
    const unsigned short* vbase = vW + ((size_t)bh * DH) * NN;

    bf16x8 qf[2];
    qf[0] = *(const bf16x8*)(qbase + (size_t)(i0 + l15) * DH + l4 * 8);
    qf[1] = *(const bf16x8*)(qbase + (size_t)(i0 + l15) * DH + 32 + l4 * 8);

    float m[4], ls[4];
    f32x4 o_acc[4] = {};
#pragma unroll
    for (int r = 0; r < 4; ++r) { m[r] = -1e30f; ls[r] = 0.f; }
    unsigned short* pl = &plds[wid][0];

    for (int jt = 0; jt < NN / 64; ++jt) {
        int j0 = jt * 64;
        f32x4 s[4] = {};
#pragma unroll
        for (int kk = 0; kk < 2; ++kk) {
            int koff = kk * 32 + l4 * 8;
#pragma unroll
            for (int f = 0; f < 4; ++f) {
                bf16x8 kf = *(const bf16x8*)(kbase + (size_t)(j0 + f * 16 + l15) * DH + koff);
                s[f] = MFMA16(qf[kk], kf, s[f]);
            }
        }
        // online softmax (row r lives in the 16-lane group sharing l>>4)
        float pm[4];
#pragma unroll
        for (int r = 0; r < 4; ++r)
            pm[r] = fmaxf(fmaxf(s[0][r], s[1][r]), fmaxf(s[2][r], s[3][r]));
#pragma unroll
        for (int dd = 1; dd < 16; dd <<= 1)
#pragma unroll
            for (int r = 0; r < 4; ++r) pm[r] = fmaxf(pm[r], __shfl_xor(pm[r], dd));
        float alpha[4];
#pragma unroll
        for (int r = 0; r < 4; ++r) {
            float mn = fmaxf(m[r], pm[r]);
            alpha[r] = __expf(m[r] - mn);
            m[r] = mn;
        }
        float p[4][4], rs[4];
#pragma unroll
        for (int f = 0; f < 4; ++f)
#pragma unroll
            for (int r = 0; r < 4; ++r) p[f][r] = __expf(s[f][r] - m[r]);
#pragma unroll
        for (int r = 0; r < 4; ++r) rs[r] = (p[0][r] + p[1][r]) + (p[2][r] + p[3][r]);
#pragma unroll
        for (int dd = 1; dd < 16; dd <<= 1)
#pragma unroll
            for (int r = 0; r < 4; ++r) rs[r] += __shfl_xor(rs[r], dd);
#pragma unroll
        for (int r = 0; r < 4; ++r) ls[r] = ls[r] * alpha[r] + rs[r];
#pragma unroll
        for (int g = 0; g < 4; ++g) {
            f32x4 t = o_acc[g];
#pragma unroll
            for (int r = 0; r < 4; ++r) t[r] *= alpha[r];
            o_acc[g] = t;
        }
        // P: C/D layout -> LDS [i][j] (swizzled) -> A-frag
#pragma unroll
        for (int f = 0; f < 4; ++f)
#pragma unroll
            for (int r = 0; r < 4; ++r) {
                int irow = l4 * 4 + r;
                unsigned int byte = (unsigned)(irow * 128 + (f * 16 + l15) * 2);
                byte ^= (unsigned)((irow & 7) << 4);
                *(unsigned short*)((char*)pl + byte) = f2bf(p[f][r]);
            }
#pragma unroll
        for (int kk = 0; kk < 2; ++kk) {
            unsigned int byte = (unsigned)(l15 * 128 + (kk * 32 + l4 * 8) * 2);
            byte ^= (unsigned)((l15 & 7) << 4);
            bf16x8 pa = *(const bf16x8*)((const char*)pl + byte);
            int joff = j0 + kk * 32 + l4 * 8;
#pragma unroll
            for (int g = 0; g < 4; ++g) {
                bf16x8 vf = *(const bf16x8*)(vbase + (size_t)(g * 16 + l15) * NN + joff);
                o_acc[g] = MFMA16(pa, vf, o_acc[g]);
            }
        }
    }
    float inv[4];
#pragma unroll
    for (int r = 0; r < 4; ++r) inv[r] = 1.f / ls[r];
    unsigned short* aop = ao + ((size_t)b * NN + i0) * HID + h * DH;
#pragma unroll
    for (int g = 0; g < 4; ++g)
#pragma unroll
        for (int r = 0; r < 4; ++r)
            aop[(size_t)(l4 * 4 + r) * HID + g * 16 + l15] = f2bf(o_acc[g][r] * inv[r]);
}

// ---------- stage 3: out = w_out @ att + b_out ----------
__global__ __launch_bounds__(256) void k_proj(
    const unsigned short* __restrict__ wo,  // [256][512]
    const unsigned short* __restrict__ ao,  // [4][2048][512]
    const float* __restrict__ bout, float* __restrict__ out)
{
    int ob = blockIdx.x;  // 0..3
    int nb = blockIdx.y;  // 0..31
    int b  = blockIdx.z;
    int wid = threadIdx.x >> 6;
    int l = threadIdx.x & 63, l15 = l & 15, l4 = l >> 4;
    int wr = wid >> 1, wc = wid & 1;
    int o0 = ob * 64 + wr * 32, n0 = nb * 64 + wc * 32;
    const unsigned short* arow = wo + (size_t)o0 * HID;
    const unsigned short* brow = ao + ((size_t)(b * NN) + n0) * HID;
    f32x4 acc[2][2] = {};
#pragma unroll
    for (int k0 = 0; k0 < HID; k0 += 32) {
        int koff = k0 + l4 * 8;
        bf16x8 a0 = *(const bf16x8*)(arow + (size_t)l15 * HID + koff);
        bf16x8 a1 = *(const bf16x8*)(arow + (size_t)(l15 + 16) * HID + koff);
        bf16x8 b0 = *(const bf16x8*)(brow + (size_t)l15 * HID + koff);
        bf16x8 b1 = *(const bf16x8*)(brow + (size_t)(l15 + 16) * HID + koff);
        acc[0][0] = MFMA16(a0, b0, acc[0][0]);
        acc[0][1] = MFMA16(a0, b1, acc[0][1]);
        acc[1][0] = MFMA16(a1, b0, acc[1][0]);
        acc[1][1] = MFMA16(a1, b1, acc[1][1]);
    }
#pragma unroll
    for (int fm = 0; fm < 2; ++fm)
#pragma unroll
        for (int fn = 0; fn < 2; ++fn)
#pragma unroll
            for (int r = 0; r < 4; ++r) {
                int o = o0 + fm * 16 + l4 * 4 + r;
                int n = n0 + fn * 16 + l15;
                out[((size_t)(b * DIMC + o)) * NN + n] = acc[fm][fn][r] + bout[o];
            }
}

// ---------- launch ----------
extern "C" void kernel_launch(void* const* d_in, const int* in_sizes, int n_in,
                              void* d_out, int out_size, void* d_ws, size_t ws_size,
                              hipStream_t stream)
{
    const float* x    = (const float*)d_in[0];
    const float* wqkv = (const float*)d_in[1];
    const float* wout = (const float*)d_in[2];
    const float* bout = (const float*)d_in[3];
    float* out = (float*)d_out;
    char* ws = (char*)d_ws;

    unsigned short* xt  = (unsigned short*)(ws + OFF_XT);
    unsigned short* wqb = (unsigned short*)(ws + OFF_WQ);
    unsigned short* wob = (unsigned short*)(ws + OFF_WO);
    unsigned short* qT  = (unsigned short*)(ws + OFF_Q);
    unsigned short* kT  = (unsigned short*)(ws + OFF_K);
    unsigned short* vW  = (unsigned short*)(ws + OFF_V);
    unsigned short* ao  = (unsigned short*)(ws + OFF_AO);

    hipLaunchKernelGGL(k_convert_w, dim3(1536), dim3(256), 0, stream, wqkv, wout, wqb, wob);
    hipLaunchKernelGGL(k_transpose_x, dim3(32, 4, 4), dim3(256), 0, stream, x, xt);
    hipLaunchKernelGGL(k_qkv, dim3(24, 32, 4), dim3(256), 0, stream, wqb, xt, qT, kT, vW);
    hipLaunchKernelGGL(k_attn, dim3(32, 32), dim3(256), 0, stream, qT, kT, vW, ao);
    hipLaunchKernelGGL(k_proj, dim3(4, 32, 4), dim3(256), 0, stream, wob, ao, bout, out);
}

// Round 3
// 258.821 us; speedup vs baseline: 1.3983x; 1.3983x over previous
//
#include <hip/hip_runtime.h>
#include <hip/hip_bf16.h>

// ---------- types ----------
using f32x4  = __attribute__((ext_vector_type(4))) float;
using f32x16 = __attribute__((ext_vector_type(16))) float;
using bf16x8 = __attribute__((ext_vector_type(8))) short;   // 8 bf16 (4 VGPRs)
using u32x2  = __attribute__((ext_vector_type(2))) unsigned int;
using u32x4  = __attribute__((ext_vector_type(4))) unsigned int;

#define MFMA16(a, b, c) __builtin_amdgcn_mfma_f32_16x16x32_bf16((a), (b), (c), 0, 0, 0)
#define MFMA32(a, b, c) __builtin_amdgcn_mfma_f32_32x32x16_bf16((a), (b), (c), 0, 0, 0)

static __device__ __forceinline__ unsigned short f2bf(float x) {
    unsigned int u = __builtin_bit_cast(unsigned int, x);
    unsigned int r = (u + 0x7fffu + ((u >> 16) & 1u)) >> 16;
    return (unsigned short)r;
}

static __device__ __forceinline__ unsigned int cvtpk_bf16(float a, float b) {
    unsigned int r;
    asm("v_cvt_pk_bf16_f32 %0, %1, %2" : "=v"(r) : "v"(a), "v"(b));
    return r;
}

static __device__ __forceinline__ float exp2_fast(float x) {
#if __has_builtin(__builtin_amdgcn_exp2f)
    return __builtin_amdgcn_exp2f(x);
#else
    return __expf(x * 0.69314718056f);
#endif
}

// exchange: x' = {hi0: x own, hi1: y from partner lane-32}; y' = {hi0: x from partner, hi1: y own}
static __device__ __forceinline__ void plswap(unsigned int& x, unsigned int& y, int hi) {
#if __has_builtin(__builtin_amdgcn_permlane32_swap)
    u32x2 r = __builtin_amdgcn_permlane32_swap(x, y, false, false);
    x = r[0]; y = r[1];
#else
    unsigned int xs = (unsigned int)__shfl_xor((int)x, 32);
    unsigned int ys = (unsigned int)__shfl_xor((int)y, 32);
    unsigned int nx = hi ? ys : x;
    unsigned int ny = hi ? y  : xs;
    x = nx; y = ny;
#endif
}

// ---------- geometry ----------
#define NB 4
#define DIMC 256
#define NN 2048
#define NH 8
#define DH 64
#define HID 512

// q scale: dhead^-0.5 * log2(e) so softmax runs in exp2 domain (exact identity)
#define QSCALE 0.18033688f

// workspace offsets (bytes)
#define OFF_XT  0u            // [4][2048][256] bf16 : 4 MiB
#define OFF_WQ  4194304u      // [1536][256]    bf16
#define OFF_WO  4980736u      // [256][512]     bf16
#define OFF_Q   5242880u      // [4][8][2048][64] bf16 (q * QSCALE)
#define OFF_K   13631488u     // [4][8][2048][64] bf16
#define OFF_V   22020096u     // [4][512][2048]   bf16 (V^T per batch)
#define OFF_AO  30408704u     // [4][2048][512]   bf16

// ---------- stage 0a: weights -> bf16 ----------
__global__ __launch_bounds__(256) void k_convert_w(
    const float* __restrict__ wqkv, const float* __restrict__ wout,
    unsigned short* __restrict__ wq_b, unsigned short* __restrict__ wo_b)
{
    int i = blockIdx.x * 256 + threadIdx.x;
    if (i < 1536 * 256) wq_b[i] = f2bf(wqkv[i]);
    if (i < 256 * 512)  wo_b[i] = f2bf(wout[i]);
}

// ---------- stage 0b: x[b][c][n] -> xt[b][n][c] bf16 ----------
__global__ __launch_bounds__(256) void k_transpose_x(
    const float* __restrict__ x, unsigned short* __restrict__ xt)
{
    __shared__ unsigned short tile[64][65];
    int nb = blockIdx.x, cb = blockIdx.y, b = blockIdx.z;
    int t = threadIdx.x;
    int tn = t & 63, tg = t >> 6;
    const float* xp = x + ((size_t)(b * DIMC + cb * 64)) * NN + nb * 64;
#pragma unroll
    for (int it = 0; it < 16; ++it) {
        int c = tg * 16 + it;
        tile[c][tn] = f2bf(xp[(size_t)c * NN + tn]);
    }
    __syncthreads();
    unsigned short* op = xt + ((size_t)(b * NN + nb * 64)) * DIMC + cb * 64;
#pragma unroll
    for (int it = 0; it < 16; ++it) {
        int n = tg * 16 + it;
        op[(size_t)n * DIMC + tn] = tile[tn][n];
    }
}

// ---------- stage 1: qkv = w_qkv @ x ----------
__global__ __launch_bounds__(256) void k_qkv(
    const unsigned short* __restrict__ wq,  // [1536][256]
    const unsigned short* __restrict__ xt,  // [4][2048][256]
    unsigned short* __restrict__ qT, unsigned short* __restrict__ kT,
    unsigned short* __restrict__ vW)
{
    int bx = blockIdx.x;          // o-tile 0..23
    int nb = blockIdx.y;          // n-tile 0..31
    int b  = blockIdx.z;
    int wid = threadIdx.x >> 6;
    int l = threadIdx.x & 63, l15 = l & 15, l4 = l >> 4;
    int o0 = bx * 64, n0 = nb * 64;
    int wr = wid >> 1, wc = wid & 1;
    f32x4 acc[2][2] = {};

    if (bx < 16) {
        const unsigned short* arow = xt + ((size_t)(b * NN + n0 + wr * 32)) * DIMC;
        const unsigned short* brow = wq + (size_t)(o0 + wc * 32) * DIMC;
#pragma unroll
        for (int k0 = 0; k0 < DIMC; k0 += 32) {
            int koff = k0 + l4 * 8;
            bf16x8 a0 = *(const bf16x8*)(arow + (size_t)l15 * DIMC + koff);
            bf16x8 a1 = *(const bf16x8*)(arow + (size_t)(l15 + 16) * DIMC + koff);
            bf16x8 b0 = *(const bf16x8*)(brow + (size_t)l15 * DIMC + koff);
            bf16x8 b1 = *(const bf16x8*)(brow + (size_t)(l15 + 16) * DIMC + koff);
            acc[0][0] = MFMA16(a0, b0, acc[0][0]);
            acc[0][1] = MFMA16(a0, b1, acc[0][1]);
            acc[1][0] = MFMA16(a1, b0, acc[1][0]);
            acc[1][1] = MFMA16(a1, b1, acc[1][1]);
        }
#pragma unroll
        for (int fm = 0; fm < 2; ++fm)
#pragma unroll
            for (int fn = 0; fn < 2; ++fn) {
                int ocol = o0 + wc * 32 + fn * 16 + l15;
#pragma unroll
                for (int r = 0; r < 4; ++r) {
                    int nrow = n0 + wr * 32 + fm * 16 + l4 * 4 + r;
                    float v = acc[fm][fn][r];
                    if (ocol < HID) {  // q: fold scale * log2(e)
                        int h = ocol >> 6, d = ocol & 63;
                        qT[(((size_t)(b * NH + h)) * NN + nrow) * DH + d] = f2bf(v * QSCALE);
                    } else {           // k
                        int o2 = ocol - HID;
                        kT[(((size_t)(b * NH + (o2 >> 6))) * NN + nrow) * DH + (o2 & 63)] = f2bf(v);
                    }
                }
            }
    } else {
        const unsigned short* arow = wq + (size_t)(o0 + wr * 32) * DIMC;
        const unsigned short* brow = xt + ((size_t)(b * NN + n0 + wc * 32)) * DIMC;
#pragma unroll
        for (int k0 = 0; k0 < DIMC; k0 += 32) {
            int koff = k0 + l4 * 8;
            bf16x8 a0 = *(const bf16x8*)(arow + (size_t)l15 * DIMC + koff);
            bf16x8 a1 = *(const bf16x8*)(arow + (size_t)(l15 + 16) * DIMC + koff);
            bf16x8 b0 = *(const bf16x8*)(brow + (size_t)l15 * DIMC + koff);
            bf16x8 b1 = *(const bf16x8*)(brow + (size_t)(l15 + 16) * DIMC + koff);
            acc[0][0] = MFMA16(a0, b0, acc[0][0]);
            acc[0][1] = MFMA16(a0, b1, acc[0][1]);
            acc[1][0] = MFMA16(a1, b0, acc[1][0]);
            acc[1][1] = MFMA16(a1, b1, acc[1][1]);
        }
#pragma unroll
        for (int fm = 0; fm < 2; ++fm)
#pragma unroll
            for (int fn = 0; fn < 2; ++fn)
#pragma unroll
                for (int r = 0; r < 4; ++r) {
                    int orow = o0 + wr * 32 + fm * 16 + l4 * 4 + r;
                    int ncol = n0 + wc * 32 + fn * 16 + l15;
                    vW[((size_t)(b * HID + orow - 1024)) * NN + ncol] = f2bf(acc[fm][fn][r]);
                }
    }
}

// ---------- stage 2: flash attention, swapped operands, 32x32x16 MFMA ----------
// grid (NN/64, 32 bh); 2 waves x 32 query rows; JBLK=32.
// S = mfma(K, Q): lane holds S[j=crow(r,hi)][i=lane&31] -> softmax per-lane.
// O^T = mfma(V^T, P^T): lane holds O[d=crow(r,hi)+32dt][i=lane&31] -> alpha per-lane.
__global__ __launch_bounds__(128) void k_attn2(
    const unsigned short* __restrict__ qT, const unsigned short* __restrict__ kT,
    const unsigned short* __restrict__ vW, unsigned short* __restrict__ ao)
{
    __shared__ unsigned short tb[2][32 * 72];   // per-wave O-transpose buffer (pad 72: 16B-aligned rows)
    int ib = blockIdx.x;
    int bh = blockIdx.y;
    int b = bh >> 3, h = bh & 7;
    int wid = threadIdx.x >> 6;
    int l = threadIdx.x & 63, li = l & 31, hi = l >> 5;
    int i0 = ib * 64 + wid * 32;

    const unsigned short* qb = qT + ((size_t)bh * NN) * DH;
    const unsigned short* kb = kT + ((size_t)bh * NN) * DH;
    const unsigned short* vb = vW + ((size_t)bh * DH) * NN;

    // Q as B-frag: col=i=li, k-slice = ks*16 + hi*8
    bf16x8 qf[4];
#pragma unroll
    for (int ks = 0; ks < 4; ++ks)
        qf[ks] = *(const bf16x8*)(qb + (size_t)(i0 + li) * DH + ks * 16 + hi * 8);

    f32x16 o0 = {}, o1 = {};
    float m = -1e30f, lsum = 0.f;

    // prefetch K(0): A-frag row=j=li, k-slice = ks*16 + hi*8
    bf16x8 kf[4];
#pragma unroll
    for (int ks = 0; ks < 4; ++ks)
        kf[ks] = *(const bf16x8*)(kb + (size_t)li * DH + ks * 16 + hi * 8);

    for (int jt = 0; jt < NN / 32; ++jt) {
        int j0 = jt * 32;
        // V A-frags (independent of softmax -> issue early): row=d=dt*32+li, k=j0+js*16+hi*8
        bf16x8 vf[2][2];
#pragma unroll
        for (int dt = 0; dt < 2; ++dt)
#pragma unroll
            for (int js = 0; js < 2; ++js)
                vf[dt][js] = *(const bf16x8*)(vb + (size_t)(dt * 32 + li) * NN + j0 + js * 16 + hi * 8);

        f32x16 s = {};
        __builtin_amdgcn_s_setprio(1);
        s = MFMA32(kf[0], qf[0], s);
        s = MFMA32(kf[1], qf[1], s);
        s = MFMA32(kf[2], qf[2], s);
        s = MFMA32(kf[3], qf[3], s);
        __builtin_amdgcn_s_setprio(0);

        // prefetch next K tile
        if (jt + 1 < NN / 32) {
#pragma unroll
            for (int ks = 0; ks < 4; ++ks)
                kf[ks] = *(const bf16x8*)(kb + (size_t)(j0 + 32 + li) * DH + ks * 16 + hi * 8);
        }

        // row max: 15 in-lane fmax + 1 cross-half exchange
        float t8[8];
#pragma unroll
        for (int q = 0; q < 8; ++q) t8[q] = fmaxf(s[2 * q], s[2 * q + 1]);
        float t4a = fmaxf(t8[0], t8[1]), t4b = fmaxf(t8[2], t8[3]);
        float t4c = fmaxf(t8[4], t8[5]), t4d = fmaxf(t8[6], t8[7]);
        float pmax = fmaxf(fmaxf(t4a, t4b), fmaxf(t4c, t4d));
        {
            unsigned int pu = __builtin_bit_cast(unsigned int, pmax), pv = pu;
            plswap(pu, pv, hi);
            pmax = fmaxf(__builtin_bit_cast(float, pu), __builtin_bit_cast(float, pv));
        }
        float mn = fmaxf(m, pmax);
        float alpha = exp2_fast(m - mn);
        m = mn;

        // P = exp2(S - m), per-lane
        float p[16];
#pragma unroll
        for (int r = 0; r < 16; ++r) p[r] = exp2_fast(s[r] - m);
        // row sum
        float u8[8];
#pragma unroll
        for (int q = 0; q < 8; ++q) u8[q] = p[2 * q] + p[2 * q + 1];
        float u4a = u8[0] + u8[1], u4b = u8[2] + u8[3], u4c = u8[4] + u8[5], u4d = u8[6] + u8[7];
        float rsum = (u4a + u4b) + (u4c + u4d);
        {
            unsigned int pu = __builtin_bit_cast(unsigned int, rsum), pv = pu;
            plswap(pu, pv, hi);
            rsum = __builtin_bit_cast(float, pu) + __builtin_bit_cast(float, pv);
        }
        lsum = lsum * alpha + rsum;

        // rescale O (per-lane scalar alpha)
#pragma unroll
        for (int r = 0; r < 16; ++r) { o0[r] *= alpha; o1[r] *= alpha; }

        // pack P -> B-frags via cvt_pk + permlane32_swap (in-register relayout)
        unsigned int W[8];
#pragma unroll
        for (int q = 0; q < 8; ++q) W[q] = cvtpk_bf16(p[2 * q], p[2 * q + 1]);
        plswap(W[0], W[2], hi); plswap(W[1], W[3], hi);
        plswap(W[4], W[6], hi); plswap(W[5], W[7], hi);
        u32x4 c0; c0[0] = W[0]; c0[1] = W[1]; c0[2] = W[2]; c0[3] = W[3];
        u32x4 c1; c1[0] = W[4]; c1[1] = W[5]; c1[2] = W[6]; c1[3] = W[7];
        bf16x8 pb0 = __builtin_bit_cast(bf16x8, c0);
        bf16x8 pb1 = __builtin_bit_cast(bf16x8, c1);

        __builtin_amdgcn_s_setprio(1);
        o0 = MFMA32(vf[0][0], pb0, o0);
        o0 = MFMA32(vf[0][1], pb1, o0);
        o1 = MFMA32(vf[1][0], pb0, o1);
        o1 = MFMA32(vf[1][1], pb1, o1);
        __builtin_amdgcn_s_setprio(0);
    }

    // epilogue: O^T[d][i] -> LDS -> ao[n][hid]
    float inv = 1.0f / lsum;
    unsigned short* tw = &tb[wid][0];
#pragma unroll
    for (int dt = 0; dt < 2; ++dt) {
        const f32x16& oo = dt ? o1 : o0;
#pragma unroll
        for (int q = 0; q < 8; ++q) {
            int r = 2 * q;
            int d0 = dt * 32 + (r & 3) + 8 * (r >> 2) + 4 * hi;   // even
            unsigned int wpk = cvtpk_bf16(oo[r] * inv, oo[r + 1] * inv);
            *(unsigned int*)((char*)tw + li * 144 + d0 * 2) = wpk;
        }
    }
    __syncthreads();
    unsigned short* aop = ao + ((size_t)b * NN + i0 + li) * HID + h * DH + hi * 32;
#pragma unroll
    for (int k = 0; k < 4; ++k) {
        bf16x8 v = *(const bf16x8*)((const char*)tw + li * 144 + (hi * 32 + k * 8) * 2);
        *(bf16x8*)(aop + k * 8) = v;
    }
}

// ---------- stage 3: out = w_out @ att + b_out ----------
__global__ __launch_bounds__(256) void k_proj(
    const unsigned short* __restrict__ wo,  // [256][512]
    const unsigned short* __restrict__ ao,  // [4][2048][512]
    const float* __restrict__ bout, float* __restrict__ out)
{
    int ob = blockIdx.x, nb = blockIdx.y, b = blockIdx.z;
    int wid = threadIdx.x >> 6;
    int l = threadIdx.x & 63, l15 = l & 15, l4 = l >> 4;
    int wr = wid >> 1, wc = wid & 1;
    int o0 = ob * 64 + wr * 32, n0 = nb * 64 + wc * 32;
    const unsigned short* arow = wo + (size_t)o0 * HID;
    const unsigned short* brow = ao + ((size_t)(b * NN) + n0) * HID;
    f32x4 acc[2][2] = {};
#pragma unroll
    for (int k0 = 0; k0 < HID; k0 += 32) {
        int koff = k0 + l4 * 8;
        bf16x8 a0 = *(const bf16x8*)(arow + (size_t)l15 * HID + koff);
        bf16x8 a1 = *(const bf16x8*)(arow + (size_t)(l15 + 16) * HID + koff);
        bf16x8 b0 = *(const bf16x8*)(brow + (size_t)l15 * HID + koff);
        bf16x8 b1 = *(const bf16x8*)(brow + (size_t)(l15 + 16) * HID + koff);
        acc[0][0] = MFMA16(a0, b0, acc[0][0]);
        acc[0][1] = MFMA16(a0, b1, acc[0][1]);
        acc[1][0] = MFMA16(a1, b0, acc[1][0]);
        acc[1][1] = MFMA16(a1, b1, acc[1][1]);
    }
#pragma unroll
    for (int fm = 0; fm < 2; ++fm)
#pragma unroll
        for (int fn = 0; fn < 2; ++fn)
#pragma unroll
            for (int r = 0; r < 4; ++r) {
                int o = o0 + fm * 16 + l4 * 4 + r;
                int n = n0 + fn * 16 + l15;
                out[((size_t)(b * DIMC + o)) * NN + n] = acc[fm][fn][r] + bout[o];
            }
}

// ---------- launch ----------
extern "C" void kernel_launch(void* const* d_in, const int* in_sizes, int n_in,
                              void* d_out, int out_size, void* d_ws, size_t ws_size,
                              hipStream_t stream)
{
    const float* x    = (const float*)d_in[0];
    const float* wqkv = (const float*)d_in[1];
    const float* wout = (const float*)d_in[2];
    const float* bout = (const float*)d_in[3];
    float* out = (float*)d_out;
    char* ws = (char*)d_ws;

    unsigned short* xt  = (unsigned short*)(ws + OFF_XT);
    unsigned short* wqb = (unsigned short*)(ws + OFF_WQ);
    unsigned short* wob = (unsigned short*)(ws + OFF_WO);
    unsigned short* qT  = (unsigned short*)(ws + OFF_Q);
    unsigned short* kT  = (unsigned short*)(ws + OFF_K);
    unsigned short* vW  = (unsigned short*)(ws + OFF_V);
    unsigned short* ao  = (unsigned short*)(ws + OFF_AO);

    hipLaunchKernelGGL(k_convert_w, dim3(1536), dim3(256), 0, stream, wqkv, wout, wqb, wob);
    hipLaunchKernelGGL(k_transpose_x, dim3(32, 4, 4), dim3(256), 0, stream, x, xt);
    hipLaunchKernelGGL(k_qkv, dim3(24, 32, 4), dim3(256), 0, stream, wqb, xt, qT, kT, vW);
    hipLaunchKernelGGL(k_attn2, dim3(32, 32), dim3(128), 0, stream, qT, kT, vW, ao);
    hipLaunchKernelGGL(k_proj, dim3(4, 32, 4), dim3(256), 0, stream, wob, ao, bout, out);
}

// Round 4
// 252.010 us; speedup vs baseline: 1.4361x; 1.0270x over previous
//
#include <hip/hip_runtime.h>
#include <hip/hip_bf16.h>

// ---------- types ----------
using f32x4  = __attribute__((ext_vector_type(4))) float;
using f32x16 = __attribute__((ext_vector_type(16))) float;
using bf16x8 = __attribute__((ext_vector_type(8))) short;   // 8 bf16 (4 VGPRs)
using u32x2  = __attribute__((ext_vector_type(2))) unsigned int;
using u32x4  = __attribute__((ext_vector_type(4))) unsigned int;

#define MFMA16(a, b, c) __builtin_amdgcn_mfma_f32_16x16x32_bf16((a), (b), (c), 0, 0, 0)
#define MFMA32(a, b, c) __builtin_amdgcn_mfma_f32_32x32x16_bf16((a), (b), (c), 0, 0, 0)

static __device__ __forceinline__ unsigned short f2bf(float x) {
    unsigned int u = __builtin_bit_cast(unsigned int, x);
    unsigned int r = (u + 0x7fffu + ((u >> 16) & 1u)) >> 16;
    return (unsigned short)r;
}

static __device__ __forceinline__ unsigned int cvtpk_bf16(float a, float b) {
    unsigned int r;
    asm("v_cvt_pk_bf16_f32 %0, %1, %2" : "=v"(r) : "v"(a), "v"(b));
    return r;
}

static __device__ __forceinline__ float exp2_fast(float x) {
#if __has_builtin(__builtin_amdgcn_exp2f)
    return __builtin_amdgcn_exp2f(x);
#else
    return __expf(x * 0.69314718056f);
#endif
}

static __device__ __forceinline__ void plswap(unsigned int& x, unsigned int& y, int hi) {
#if __has_builtin(__builtin_amdgcn_permlane32_swap)
    u32x2 r = __builtin_amdgcn_permlane32_swap(x, y, false, false);
    x = r[0]; y = r[1];
#else
    unsigned int xs = (unsigned int)__shfl_xor((int)x, 32);
    unsigned int ys = (unsigned int)__shfl_xor((int)y, 32);
    unsigned int nx = hi ? ys : x;
    unsigned int ny = hi ? y  : xs;
    x = nx; y = ny;
#endif
}

// ---------- geometry ----------
#define NB 4
#define DIMC 256
#define NN 2048
#define NH 8
#define DH 64
#define HID 512

// q scale: dhead^-0.5 * log2(e) so softmax runs in exp2 domain
#define QSCALE 0.18033688f

// workspace offsets (bytes)
#define OFF_XT  0u            // [4][2048][256] bf16 : 4 MiB
#define OFF_WQ  4194304u      // [1536][256]    bf16
#define OFF_WO  4980736u      // [256][512]     bf16
#define OFF_Q   5242880u      // [4][8][2048][64] bf16 (q * QSCALE)
#define OFF_K   13631488u     // [4][8][2048][64] bf16
#define OFF_V   22020096u     // [4][512][2048]   bf16 (V^T per batch)
#define OFF_AO  30408704u     // [4][2048][512]   bf16

// ---------- stage 0: x transpose->bf16 + weight convert (fused) ----------
// grid (32,4,4) x 256 thr. Each thread additionally converts one float4 of weights.
__global__ __launch_bounds__(256) void k_prep(
    const float* __restrict__ x, const float* __restrict__ wqkv,
    const float* __restrict__ wout,
    unsigned short* __restrict__ xt, unsigned short* __restrict__ wq_b,
    unsigned short* __restrict__ wo_b)
{
    // weights: 1536*256/4 = 98304 float4 (wq) + 256*512/4 = 32768 (wo) = 131072 = 512*256
    int wg = blockIdx.x + 32 * blockIdx.y + 128 * blockIdx.z;
    int tid = wg * 256 + threadIdx.x;
    if (tid < 98304) {
        float4 v = ((const float4*)wqkv)[tid];
        u32x2 pk; pk[0] = cvtpk_bf16(v.x, v.y); pk[1] = cvtpk_bf16(v.z, v.w);
        *(u32x2*)(wq_b + (size_t)tid * 4) = pk;
    } else {
        int t2 = tid - 98304;
        float4 v = ((const float4*)wout)[t2];
        u32x2 pk; pk[0] = cvtpk_bf16(v.x, v.y); pk[1] = cvtpk_bf16(v.z, v.w);
        *(u32x2*)(wo_b + (size_t)t2 * 4) = pk;
    }

    __shared__ unsigned short tile[64][65];
    int nb = blockIdx.x, cb = blockIdx.y, b = blockIdx.z;
    int t = threadIdx.x;
    int tn = t & 63, tg = t >> 6;
    const float* xp = x + ((size_t)(b * DIMC + cb * 64)) * NN + nb * 64;
#pragma unroll
    for (int it = 0; it < 16; ++it) {
        int c = tg * 16 + it;
        tile[c][tn] = f2bf(xp[(size_t)c * NN + tn]);
    }
    __syncthreads();
    unsigned short* op = xt + ((size_t)(b * NN + nb * 64)) * DIMC + cb * 64;
#pragma unroll
    for (int it = 0; it < 16; ++it) {
        int n = tg * 16 + it;
        op[(size_t)n * DIMC + tn] = tile[tn][n];
    }
}

// ---------- stage 1: qkv = w_qkv @ x ----------
__global__ __launch_bounds__(256) void k_qkv(
    const unsigned short* __restrict__ wq,  // [1536][256]
    const unsigned short* __restrict__ xt,  // [4][2048][256]
    unsigned short* __restrict__ qT, unsigned short* __restrict__ kT,
    unsigned short* __restrict__ vW)
{
    int bx = blockIdx.x;          // o-tile 0..23
    int nb = blockIdx.y;          // n-tile 0..31
    int b  = blockIdx.z;
    int wid = threadIdx.x >> 6;
    int l = threadIdx.x & 63, l15 = l & 15, l4 = l >> 4;
    int o0 = bx * 64, n0 = nb * 64;
    int wr = wid >> 1, wc = wid & 1;
    f32x4 acc[2][2] = {};

    if (bx < 16) {
        const unsigned short* arow = xt + ((size_t)(b * NN + n0 + wr * 32)) * DIMC;
        const unsigned short* brow = wq + (size_t)(o0 + wc * 32) * DIMC;
#pragma unroll
        for (int k0 = 0; k0 < DIMC; k0 += 32) {
            int koff = k0 + l4 * 8;
            bf16x8 a0 = *(const bf16x8*)(arow + (size_t)l15 * DIMC + koff);
            bf16x8 a1 = *(const bf16x8*)(arow + (size_t)(l15 + 16) * DIMC + koff);
            bf16x8 b0 = *(const bf16x8*)(brow + (size_t)l15 * DIMC + koff);
            bf16x8 b1 = *(const bf16x8*)(brow + (size_t)(l15 + 16) * DIMC + koff);
            acc[0][0] = MFMA16(a0, b0, acc[0][0]);
            acc[0][1] = MFMA16(a0, b1, acc[0][1]);
            acc[1][0] = MFMA16(a1, b0, acc[1][0]);
            acc[1][1] = MFMA16(a1, b1, acc[1][1]);
        }
#pragma unroll
        for (int fm = 0; fm < 2; ++fm)
#pragma unroll
            for (int fn = 0; fn < 2; ++fn) {
                int ocol = o0 + wc * 32 + fn * 16 + l15;
#pragma unroll
                for (int r = 0; r < 4; ++r) {
                    int nrow = n0 + wr * 32 + fm * 16 + l4 * 4 + r;
                    float v = acc[fm][fn][r];
                    if (ocol < HID) {  // q: fold scale * log2(e)
                        int h = ocol >> 6, d = ocol & 63;
                        qT[(((size_t)(b * NH + h)) * NN + nrow) * DH + d] = f2bf(v * QSCALE);
                    } else {           // k
                        int o2 = ocol - HID;
                        kT[(((size_t)(b * NH + (o2 >> 6))) * NN + nrow) * DH + (o2 & 63)] = f2bf(v);
                    }
                }
            }
    } else {
        const unsigned short* arow = wq + (size_t)(o0 + wr * 32) * DIMC;
        const unsigned short* brow = xt + ((size_t)(b * NN + n0 + wc * 32)) * DIMC;
#pragma unroll
        for (int k0 = 0; k0 < DIMC; k0 += 32) {
            int koff = k0 + l4 * 8;
            bf16x8 a0 = *(const bf16x8*)(arow + (size_t)l15 * DIMC + koff);
            bf16x8 a1 = *(const bf16x8*)(arow + (size_t)(l15 + 16) * DIMC + koff);
            bf16x8 b0 = *(const bf16x8*)(brow + (size_t)l15 * DIMC + koff);
            bf16x8 b1 = *(const bf16x8*)(brow + (size_t)(l15 + 16) * DIMC + koff);
            acc[0][0] = MFMA16(a0, b0, acc[0][0]);
            acc[0][1] = MFMA16(a0, b1, acc[0][1]);
            acc[1][0] = MFMA16(a1, b0, acc[1][0]);
            acc[1][1] = MFMA16(a1, b1, acc[1][1]);
        }
#pragma unroll
        for (int fm = 0; fm < 2; ++fm)
#pragma unroll
            for (int fn = 0; fn < 2; ++fn)
#pragma unroll
                for (int r = 0; r < 4; ++r) {
                    int orow = o0 + wr * 32 + fm * 16 + l4 * 4 + r;
                    int ncol = n0 + wc * 32 + fn * 16 + l15;
                    vW[((size_t)(b * HID + orow - 1024)) * NN + ncol] = f2bf(acc[fm][fn][r]);
                }
    }
}

// ---------- stage 2: flash attention, swapped operands, 32x32x16 MFMA ----------
// 1D grid 1024, XCD-swizzled: wg&7 = XCD, 4 bh per XCD -> K/V L2-resident (2 MB/XCD).
// 2 waves x 32 query rows; JBLK=32; defer-max (T13, exp2-domain THR=8).
__global__ __launch_bounds__(128) void k_attn3(
    const unsigned short* __restrict__ qT, const unsigned short* __restrict__ kT,
    const unsigned short* __restrict__ vW, unsigned short* __restrict__ ao)
{
    __shared__ unsigned short tb[2][32 * 72];
    int wg = blockIdx.x;            // 0..1023
    int xcd = wg & 7;
    int idx = wg >> 3;              // 0..127
    int bh  = xcd * 4 + (idx & 3);  // all 32 i-tiles of bh stay on one XCD
    int ib  = idx >> 2;             // 0..31
    int b = bh >> 3, h = bh & 7;
    int wid = threadIdx.x >> 6;
    int l = threadIdx.x & 63, li = l & 31, hi = l >> 5;
    int i0 = ib * 64 + wid * 32;

    const unsigned short* qb = qT + ((size_t)bh * NN) * DH;
    const unsigned short* kb = kT + ((size_t)bh * NN) * DH;
    const unsigned short* vb = vW + ((size_t)bh * DH) * NN;

    bf16x8 qf[4];
#pragma unroll
    for (int ks = 0; ks < 4; ++ks)
        qf[ks] = *(const bf16x8*)(qb + (size_t)(i0 + li) * DH + ks * 16 + hi * 8);

    f32x16 o0 = {}, o1 = {};
    float m = -1e30f, lsum = 0.f;

    bf16x8 kf[4];
#pragma unroll
    for (int ks = 0; ks < 4; ++ks)
        kf[ks] = *(const bf16x8*)(kb + (size_t)li * DH + ks * 16 + hi * 8);

    for (int jt = 0; jt < NN / 32; ++jt) {
        int j0 = jt * 32;
        bf16x8 vf[2][2];
#pragma unroll
        for (int dt = 0; dt < 2; ++dt)
#pragma unroll
            for (int js = 0; js < 2; ++js)
                vf[dt][js] = *(const bf16x8*)(vb + (size_t)(dt * 32 + li) * NN + j0 + js * 16 + hi * 8);

        f32x16 s = {};
        __builtin_amdgcn_s_setprio(1);
        s = MFMA32(kf[0], qf[0], s);
        s = MFMA32(kf[1], qf[1], s);
        s = MFMA32(kf[2], qf[2], s);
        s = MFMA32(kf[3], qf[3], s);
        __builtin_amdgcn_s_setprio(0);

        if (jt + 1 < NN / 32) {
#pragma unroll
            for (int ks = 0; ks < 4; ++ks)
                kf[ks] = *(const bf16x8*)(kb + (size_t)(j0 + 32 + li) * DH + ks * 16 + hi * 8);
        }

        // per-lane row max over 16 rows, then cross-half exchange -> per-query max
        float t8[8];
#pragma unroll
        for (int q = 0; q < 8; ++q) t8[q] = fmaxf(s[2 * q], s[2 * q + 1]);
        float t4a = fmaxf(t8[0], t8[1]), t4b = fmaxf(t8[2], t8[3]);
        float t4c = fmaxf(t8[4], t8[5]), t4d = fmaxf(t8[6], t8[7]);
        float pmax = fmaxf(fmaxf(t4a, t4b), fmaxf(t4c, t4d));
        {
            unsigned int pu = __builtin_bit_cast(unsigned int, pmax), pv = pu;
            plswap(pu, pv, hi);
            pmax = fmaxf(__builtin_bit_cast(float, pu), __builtin_bit_cast(float, pv));
        }

        // defer-max: only rescale when the running max grew by > 8 (exp2 domain, P <= 256)
        if (!__all(pmax - m <= 8.0f)) {
            float mn = fmaxf(m, pmax);
            float alpha = exp2_fast(m - mn);
            m = mn;
            lsum *= alpha;
#pragma unroll
            for (int r = 0; r < 16; ++r) { o0[r] *= alpha; o1[r] *= alpha; }
        }

        float p[16];
#pragma unroll
        for (int r = 0; r < 16; ++r) p[r] = exp2_fast(s[r] - m);
        float u8[8];
#pragma unroll
        for (int q = 0; q < 8; ++q) u8[q] = p[2 * q] + p[2 * q + 1];
        float u4a = u8[0] + u8[1], u4b = u8[2] + u8[3], u4c = u8[4] + u8[5], u4d = u8[6] + u8[7];
        float rsum = (u4a + u4b) + (u4c + u4d);
        {
            unsigned int pu = __builtin_bit_cast(unsigned int, rsum), pv = pu;
            plswap(pu, pv, hi);
            rsum = __builtin_bit_cast(float, pu) + __builtin_bit_cast(float, pv);
        }
        lsum += rsum;

        // pack P -> B-frags in-register
        unsigned int W[8];
#pragma unroll
        for (int q = 0; q < 8; ++q) W[q] = cvtpk_bf16(p[2 * q], p[2 * q + 1]);
        plswap(W[0], W[2], hi); plswap(W[1], W[3], hi);
        plswap(W[4], W[6], hi); plswap(W[5], W[7], hi);
        u32x4 c0; c0[0] = W[0]; c0[1] = W[1]; c0[2] = W[2]; c0[3] = W[3];
        u32x4 c1; c1[0] = W[4]; c1[1] = W[5]; c1[2] = W[6]; c1[3] = W[7];
        bf16x8 pb0 = __builtin_bit_cast(bf16x8, c0);
        bf16x8 pb1 = __builtin_bit_cast(bf16x8, c1);

        __builtin_amdgcn_s_setprio(1);
        o0 = MFMA32(vf[0][0], pb0, o0);
        o0 = MFMA32(vf[0][1], pb1, o0);
        o1 = MFMA32(vf[1][0], pb0, o1);
        o1 = MFMA32(vf[1][1], pb1, o1);
        __builtin_amdgcn_s_setprio(0);
    }

    // epilogue: O^T[d][i] -> LDS -> ao[n][hid]
    float inv = 1.0f / lsum;
    unsigned short* tw = &tb[wid][0];
#pragma unroll
    for (int dt = 0; dt < 2; ++dt) {
        const f32x16& oo = dt ? o1 : o0;
#pragma unroll
        for (int q = 0; q < 8; ++q) {
            int r = 2 * q;
            int d0 = dt * 32 + (r & 3) + 8 * (r >> 2) + 4 * hi;
            unsigned int wpk = cvtpk_bf16(oo[r] * inv, oo[r + 1] * inv);
            *(unsigned int*)((char*)tw + li * 144 + d0 * 2) = wpk;
        }
    }
    __syncthreads();
    unsigned short* aop = ao + ((size_t)b * NN + i0 + li) * HID + h * DH + hi * 32;
#pragma unroll
    for (int k = 0; k < 4; ++k) {
        bf16x8 v = *(const bf16x8*)((const char*)tw + li * 144 + (hi * 32 + k * 8) * 2);
        *(bf16x8*)(aop + k * 8) = v;
    }
}

// ---------- stage 3: out = w_out @ att + b_out ----------
__global__ __launch_bounds__(256) void k_proj(
    const unsigned short* __restrict__ wo,  // [256][512]
    const unsigned short* __restrict__ ao,  // [4][2048][512]
    const float* __restrict__ bout, float* __restrict__ out)
{
    int ob = blockIdx.x, nb = blockIdx.y, b = blockIdx.z;
    int wid = threadIdx.x >> 6;
    int l = threadIdx.x & 63, l15 = l & 15, l4 = l >> 4;
    int wr = wid >> 1, wc = wid & 1;
    int o0 = ob * 64 + wr * 32, n0 = nb * 64 + wc * 32;
    const unsigned short* arow = wo + (size_t)o0 * HID;
    const unsigned short* brow = ao + ((size_t)(b * NN) + n0) * HID;
    f32x4 acc[2][2] = {};
#pragma unroll
    for (int k0 = 0; k0 < HID; k0 += 32) {
        int koff = k0 + l4 * 8;
        bf16x8 a0 = *(const bf16x8*)(arow + (size_t)l15 * HID + koff);
        bf16x8 a1 = *(const bf16x8*)(arow + (size_t)(l15 + 16) * HID + koff);
        bf16x8 b0 = *(const bf16x8*)(brow + (size_t)l15 * HID + koff);
        bf16x8 b1 = *(const bf16x8*)(brow + (size_t)(l15 + 16) * HID + koff);
        acc[0][0] = MFMA16(a0, b0, acc[0][0]);
        acc[0][1] = MFMA16(a0, b1, acc[0][1]);
        acc[1][0] = MFMA16(a1, b0, acc[1][0]);
        acc[1][1] = MFMA16(a1, b1, acc[1][1]);
    }
#pragma unroll
    for (int fm = 0; fm < 2; ++fm)
#pragma unroll
        for (int fn = 0; fn < 2; ++fn)
#pragma unroll
            for (int r = 0; r < 4; ++r) {
                int o = o0 + fm * 16 + l4 * 4 + r;
                int n = n0 + fn * 16 + l15;
                out[((size_t)(b * DIMC + o)) * NN + n] = acc[fm][fn][r] + bout[o];
            }
}

// ---------- launch ----------
extern "C" void kernel_launch(void* const* d_in, const int* in_sizes, int n_in,
                              void* d_out, int out_size, void* d_ws, size_t ws_size,
                              hipStream_t stream)
{
    const float* x    = (const float*)d_in[0];
    const float* wqkv = (const float*)d_in[1];
    const float* wout = (const float*)d_in[2];
    const float* bout = (const float*)d_in[3];
    float* out = (float*)d_out;
    char* ws = (char*)d_ws;

    unsigned short* xt  = (unsigned short*)(ws + OFF_XT);
    unsigned short* wqb = (unsigned short*)(ws + OFF_WQ);
    unsigned short* wob = (unsigned short*)(ws + OFF_WO);
    unsigned short* qT  = (unsigned short*)(ws + OFF_Q);
    unsigned short* kT  = (unsigned short*)(ws + OFF_K);
    unsigned short* vW  = (unsigned short*)(ws + OFF_V);
    unsigned short* ao  = (unsigned short*)(ws + OFF_AO);

    hipLaunchKernelGGL(k_prep, dim3(32, 4, 4), dim3(256), 0, stream, x, wqkv, wout, xt, wqb, wob);
    hipLaunchKernelGGL(k_qkv, dim3(24, 32, 4), dim3(256), 0, stream, wqb, xt, qT, kT, vW);
    hipLaunchKernelGGL(k_attn3, dim3(1024), dim3(128), 0, stream, qT, kT, vW, ao);
    hipLaunchKernelGGL(k_proj, dim3(4, 32, 4), dim3(256), 0, stream, wob, ao, bout, out);
}